// Round 5
// baseline (183.714 us; speedup 1.0000x reference)
//
#include <hip/hip_runtime.h>
#include <hip/hip_bf16.h>

// PhraseClassifier R15.
//   R14 post-mortem: contiguous stage changed NOTHING (control FETCH/WRITE
//   held) -> stage theory dead. dur_us decomposition: kernels ~90us + two
//   ~41us harness workspace-poison fills (~82us, fixed). span_eval ~40us =
//   268MB at 6.7 TB/s = L3 rate -> the %8 XCD swizzle is NOT delivering L2
//   residency (block->XCD mapping assumption likely wrong; swizzle then
//   SCATTERS sorted chunks). proj_gemm: VGPR_Count=64 shows compiler kept B
//   frags just-in-time -> 16 exposed L2 latencies/wave behind vmcnt drains.
//   R15 (two changes, DIFFERENT kernels, separately attributable):
//     1. proj_gemm: depth-3 software-pipelined B fragments (named sets,
//        static indices; full unroll renames rotation away; counted vmcnt).
//     2. span_eval: drop XCD swizzle, keep bid-sort (dispatch-order temporal
//        locality: resident block wavefront shares 2-3 bid slabs per L2).
//   Controls: proj FETCH/WRITE unchanged, VGPR ~96-120; span should drop to
//   12-18us. If proj flat with VGPR up -> B latency not binding.

typedef float f32x4 __attribute__((ext_vector_type(4)));
typedef float f32x2 __attribute__((ext_vector_type(2)));
typedef __bf16 bf16x8 __attribute__((ext_vector_type(8)));
typedef __bf16 bf16x4 __attribute__((ext_vector_type(4)));

__device__ __forceinline__ unsigned short f2bf(float f) {
  unsigned int u = __float_as_uint(f);
  u += 0x7fffu + ((u >> 16) & 1u);   // RNE
  return (unsigned short)(u >> 16);
}
__device__ __forceinline__ float bf2f(unsigned int lo16) {
  return __uint_as_float(lo16 << 16);
}

// ---- prep: W1 blocking (blocks 0..255) + span bid histogram (256..383) ----
__global__ void prep(const float* __restrict__ W1,
                     unsigned short* __restrict__ W1b,
                     const int* __restrict__ bids, int* __restrict__ ghist,
                     int nspans) {
  __shared__ int h[32];
  int t = threadIdx.x;
  if (blockIdx.x < 256) {
    int idx = blockIdx.x * 256 + t;             // 0..65535
    int kc = idx & 3;
    int n  = (idx >> 2) & 511;
    int c  = idx >> 11;
    int k0 = c * 32 + kc * 8;
    unsigned short tmp[8];
#pragma unroll
    for (int j = 0; j < 8; ++j)
      tmp[j] = f2bf(W1[(k0 + j) * 512 + n]);
    *(uint4*)(W1b + c * 16384 + n * 32 + kc * 8) = *(uint4*)tmp;
  } else {
    if (t < 32) h[t] = 0;
    __syncthreads();
    int base = (blockIdx.x - 256) * 1024;
#pragma unroll
    for (int i = 0; i < 4; ++i) {
      int idx = base + t + i * 256;
      if (idx < nspans) atomicAdd(&h[bids[idx]], 1);
    }
    __syncthreads();
    if (t < 32) atomicAdd(&ghist[t], h[t]);
  }
}

// ---- span scatter (counting sort by bid into sidx) ----
__global__ void span_scatter(const int* __restrict__ bids,
                             const int* __restrict__ ghist,
                             int* __restrict__ gslot,
                             int* __restrict__ sidx, int nspans) {
  __shared__ int lh[32], lbase[32], lcur[32];
  int t = threadIdx.x;
  if (t < 32) lh[t] = 0;
  __syncthreads();
  int base = blockIdx.x * 512;
  int myb[2];
#pragma unroll
  for (int i = 0; i < 2; ++i) {
    int idx = base + t + i * 256;
    myb[i] = (idx < nspans) ? bids[idx] : -1;
    if (myb[i] >= 0) atomicAdd(&lh[myb[i]], 1);
  }
  __syncthreads();
  if (t < 32) {
    int pre = 0;
    for (int j = 0; j < t; ++j) pre += ghist[j];   // exclusive prefix
    lbase[t] = pre + atomicAdd(&gslot[t], lh[t]);  // reserve chunk
    lcur[t] = 0;
  }
  __syncthreads();
#pragma unroll
  for (int i = 0; i < 2; ++i) {
    int b = myb[i];
    if (b >= 0) {
      int pos = lbase[b] + atomicAdd(&lcur[b], 1);
      sidx[pos] = base + t + i * 256;
    }
  }
}

// ---------------- proj_gemm: 64M x 512N per block, one K-half ----------------
// 512 threads / 8 waves, wave w owns cols [w*64, w*64+64): acc 4m x 4n.
// A staged in LDS (row-major, APITCH 522; contiguous 1KB stage loads).
// B frags DIRECT global->VGPR from blocked W1b, DEPTH-3 software pipeline.
#define APITCH 522
__global__ __launch_bounds__(512, 4) void proj_gemm(
    const float* __restrict__ hidden,        // [16384][1024]
    const unsigned short* __restrict__ w1b,  // blocked [32][512][32] bf16
    unsigned char* __restrict__ Wq) {        // [16384][1024] fp8: [U[r] | V[r+32]]
  __shared__ __align__(16) unsigned short AH[64 * APITCH];  // 66816 B
  unsigned short* Eb = AH;                   // overlay [8][32][72] = 36864 B

  const int t = threadIdx.x;                 // 0..511
  const int lane = t & 63;
  const int w = t >> 6;                      // 0..7
  const int r0 = blockIdx.x << 6;
  const int hk = blockIdx.y << 9;            // 0 (U) or 512 (V)
  const int q = lane >> 4;                   // k-sub 0..3
  const int m = lane & 15;

  // ---- stage A: wave w stages rows w*8..w*8+7; per row 2 instructions,
  // lane l covers bytes [l*16, l*16+16) of a 1KB half-row -> contiguous.
  {
    const float* gbase = hidden + hk + (lane << 2);
#pragma unroll
    for (int i = 0; i < 8; ++i) {
      int row = (w << 3) + i;
      const float* rp = gbase + ((r0 + row) << 10);
#pragma unroll
      for (int hh = 0; hh < 2; ++hh) {
        float4 f = *(const float4*)(rp + (hh << 8));
        bf16x4 hv;
        hv[0] = (__bf16)f.x; hv[1] = (__bf16)f.y;
        hv[2] = (__bf16)f.z; hv[3] = (__bf16)f.w;
        *(bf16x4*)(AH + row * APITCH + (hh << 8) + (lane << 2)) = hv;
      }
    }
  }
  __syncthreads();

  int boffn[4];
#pragma unroll
  for (int nt = 0; nt < 4; ++nt)
    boffn[nt] = (((w << 6) + (nt << 4) + m) << 5) + (q << 3);
  const unsigned short* w1base = w1b + (blockIdx.y << 18);

  f32x4 acc[4][4];
#pragma unroll
  for (int i = 0; i < 4; ++i)
#pragma unroll
    for (int j = 0; j < 4; ++j) acc[i][j] = (f32x4){0.f, 0.f, 0.f, 0.f};

  // ---- depth-3 B pipeline prologue: tiles 0,1,2 in flight ----
  bf16x8 bp0[4], bp1[4], bp2[4];
#pragma unroll
  for (int nt = 0; nt < 4; ++nt)
    bp0[nt] = *(const bf16x8*)(w1base + (0 << 14) + boffn[nt]);
#pragma unroll
  for (int nt = 0; nt < 4; ++nt)
    bp1[nt] = *(const bf16x8*)(w1base + (1 << 14) + boffn[nt]);
#pragma unroll
  for (int nt = 0; nt < 4; ++nt)
    bp2[nt] = *(const bf16x8*)(w1base + (2 << 14) + boffn[nt]);

#pragma unroll
  for (int it = 0; it < 16; ++it) {
    // issue prefetch for it+3 FIRST (no dependency on current MFMAs)
    bf16x8 bn[4];
    if (it + 3 < 16) {
      const unsigned short* btn = w1base + ((it + 3) << 14);
#pragma unroll
      for (int nt = 0; nt < 4; ++nt)
        bn[nt] = *(const bf16x8*)(btn + boffn[nt]);
    }
    bf16x8 af[4];
#pragma unroll
    for (int mt = 0; mt < 4; ++mt)
      af[mt] = *(const bf16x8*)(AH + ((mt << 4) + m) * APITCH + (it << 5) + (q << 3));
#pragma unroll
    for (int mt = 0; mt < 4; ++mt)
#pragma unroll
      for (int nt = 0; nt < 4; ++nt)
        acc[mt][nt] = __builtin_amdgcn_mfma_f32_16x16x32_bf16(af[mt], bp0[nt],
                                                              acc[mt][nt], 0, 0, 0);
    // rotate (full unroll -> pure SSA renames, no moves)
#pragma unroll
    for (int nt = 0; nt < 4; ++nt) {
      bp0[nt] = bp1[nt];
      bp1[nt] = bp2[nt];
    }
    if (it + 3 < 16)
#pragma unroll
      for (int nt = 0; nt < 4; ++nt) bp2[nt] = bn[nt];
  }
  __syncthreads();   // all waves done reading AH -> Eb may overlay it

  // ---- epilogue: wave-local repack (32 rows x 64 cols per pass) + fp8 stores
  // C/D layout: col = lane&15, row = (lane>>4)*4 + reg.
  unsigned short* Ew = Eb + w * (32 * 72);   // wave-local band, 16B-aligned
#pragma unroll
  for (int pass = 0; pass < 2; ++pass) {
#pragma unroll
    for (int mh = 0; mh < 2; ++mh) {
      int mt = (pass << 1) + mh;
#pragma unroll
      for (int r = 0; r < 4; ++r) {
        int rr = (mh << 4) + ((lane >> 4) << 2) + r;   // 0..31
#pragma unroll
        for (int nt = 0; nt < 4; ++nt)
          Ew[rr * 72 + (nt << 4) + m] = f2bf(acc[mt][nt][r]);
      }
    }
    // 32 rows x 64 cols = 256 8-byte tasks = 4 iters x 64 lanes
#pragma unroll
    for (int i = 0; i < 4; ++i) {
      int task = (i << 6) + lane;
      int rr = task >> 3;                    // 0..31
      int ck = task & 7;                     // 0..7
      uint4 v = *(const uint4*)&Ew[rr * 72 + (ck << 3)];
      float f0 = bf2f(v.x & 0xffff), f1 = bf2f(v.x >> 16);
      float f2 = bf2f(v.y & 0xffff), f3 = bf2f(v.y >> 16);
      float f4 = bf2f(v.z & 0xffff), f5 = bf2f(v.z >> 16);
      float f6 = bf2f(v.w & 0xffff), f7 = bf2f(v.w >> 16);
      uint2 o;
      o.x = __builtin_amdgcn_cvt_pk_fp8_f32(f0, f1, 0, false);
      o.x = __builtin_amdgcn_cvt_pk_fp8_f32(f2, f3, o.x, true);
      o.y = __builtin_amdgcn_cvt_pk_fp8_f32(f4, f5, 0, false);
      o.y = __builtin_amdgcn_cvt_pk_fp8_f32(f6, f7, o.y, true);
      int grow = r0 + (pass << 5) + rr;
      int col = (w << 6) + (ck << 3);
      if (hk == 0) {
        *(uint2*)(Wq + (grow << 10) + col) = o;              // U[r]
      } else if (grow >= 32) {
        *(uint2*)(Wq + ((grow - 32) << 10) + 512 + col) = o; // V[r] -> row r-32
      }
    }
    // Ew band is wave-local; in-order within wave between passes
  }
}

// ---------------- span_eval: 1 span per half-wave, bid-sorted order ----------
#define SPB 64
__global__ __launch_bounds__(256) void span_eval(
    const unsigned char* __restrict__ Wq,
    const int* __restrict__ sidx,
    const int* __restrict__ bids, const int* __restrict__ begins,
    const int* __restrict__ ends, const int* __restrict__ flags,
    const float* __restrict__ weights,
    const float* __restrict__ b1, const float* __restrict__ w2,
    const float* __restrict__ b2, float* __restrict__ partials) {
  __shared__ int oB[SPB], oE[SPB], sfl[SPB];
  __shared__ float swt[SPB];
  __shared__ float red[4][3];
  const int t = threadIdx.x;
  const int lane = t & 63;
  const int w = t >> 6;
  const int h = lane >> 5;          // half-wave
  const int hl = lane & 31;

  // NO XCD swizzle (R15): consecutive blocks process consecutive bid-sorted
  // spans; the resident dispatch wavefront shares 2-3 bid slabs -> each
  // XCD's L2 caches those slabs regardless of block->XCD mapping.
  const int sbase = blockIdx.x * SPB;

  if (t < SPB) {
    int s = sidx[sbase + t];
    int b = bids[s], bg = begins[s], en = ends[s];
    oB[t] = (((bg - 1) << 5) + b) << 10;   // row b-1: [U[b-1] | V[b]]
    oE[t] = (((en - 1) << 5) + b) << 10;   // row e-1: [U[e-1] | V[e]]
    sfl[t] = flags[s];
    swt[t] = weights[s];
  }
  __syncthreads();

  const int sp0 = ((w << 1) + h) << 3;   // my half-wave's first span (block-local)
  const int c0 = hl << 4;                // 16 u-cols per lane
  float b1v[16], w2v[16];
#pragma unroll
  for (int qq = 0; qq < 4; ++qq) {
    float4 bv = *(const float4*)(b1 + c0 + (qq << 2));
    float4 wv = *(const float4*)(w2 + c0 + (qq << 2));
    b1v[(qq << 2) + 0] = bv.x; b1v[(qq << 2) + 1] = bv.y;
    b1v[(qq << 2) + 2] = bv.z; b1v[(qq << 2) + 3] = bv.w;
    w2v[(qq << 2) + 0] = wv.x; w2v[(qq << 2) + 1] = wv.y;
    w2v[(qq << 2) + 2] = wv.z; w2v[(qq << 2) + 3] = wv.w;
  }

  auto dec = [](unsigned int v, float* f) {
    f32x2 a = __builtin_amdgcn_cvt_pk_f32_fp8(v, false);
    f32x2 b = __builtin_amdgcn_cvt_pk_f32_fp8(v, true);
    f[0] = a[0]; f[1] = a[1]; f[2] = b[0]; f[3] = b[1];
  };

  uint4 BU[3], BV[3], EU[3], EV[3];
  auto ld = [&](int slot, int j) {
    int ob = oB[sp0 + j], oe = oE[sp0 + j];
    BU[slot] = *(const uint4*)(Wq + ob + c0);        // U[b-1] chunk
    BV[slot] = *(const uint4*)(Wq + ob + 512 + c0);  // V[b]   chunk
    EU[slot] = *(const uint4*)(Wq + oe + c0);        // U[e-1] chunk
    EV[slot] = *(const uint4*)(Wq + oe + 512 + c0);  // V[e]   chunk
  };
  ld(0, 0); ld(1, 1); ld(2, 2);

  float mylogit = 0.f;
#pragma unroll
  for (int j = 0; j < 8; ++j) {
    const int slot = j % 3;
    float buf[16], bvf[16], euf[16], evf[16];
    dec(BU[slot].x, buf); dec(BU[slot].y, buf + 4);
    dec(BU[slot].z, buf + 8); dec(BU[slot].w, buf + 12);
    dec(BV[slot].x, bvf); dec(BV[slot].y, bvf + 4);
    dec(BV[slot].z, bvf + 8); dec(BV[slot].w, bvf + 12);
    dec(EU[slot].x, euf); dec(EU[slot].y, euf + 4);
    dec(EU[slot].z, euf + 8); dec(EU[slot].w, euf + 12);
    dec(EV[slot].x, evf); dec(EV[slot].y, evf + 4);
    dec(EV[slot].z, evf + 8); dec(EV[slot].w, evf + 12);
    if (j + 3 < 8) ld(slot, j + 3);
    float sv = 0.f;
#pragma unroll
    for (int k = 0; k < 16; ++k) {
      float zp = euf[k] - buf[k] + bvf[k] - evf[k] + b1v[k];
      sv += fmaxf(zp, 0.f) * w2v[k];
    }
    sv += __shfl_xor(sv, 1);
    sv += __shfl_xor(sv, 2);
    sv += __shfl_xor(sv, 4);
    sv += __shfl_xor(sv, 8);
    sv += __shfl_xor(sv, 16);       // reduce within half-wave
    if (hl == j) mylogit = sv;      // lane h*32+j parks span sp0+j
  }

  // span w*16+l (l<16) parked at lane ((l&8)<<2)+(l&7)
  mylogit = __shfl(mylogit, ((lane & 8) << 2) + (lane & 7));

  float pos_t = 0.f, neg_t = 0.f, cnt_t = 0.f;
  if (lane < 16) {
    int sl = (w << 4) + lane;       // block-local span id
    float logit = mylogit + b2[0];
    float p = 1.f / (1.f + expf(-logit));
    p = fminf(fmaxf(p, 1e-7f), 1.f - 1e-7f);
    int fl = sfl[sl];
    float bce = (fl == 1) ? -logf(p) : -logf(1.f - p);
    float term = swt[sl] * bce;
    pos_t = (fl == 1) ? term : 0.f;
    neg_t = (fl == 1) ? 0.f : term;
    cnt_t = (fl == 1) ? 1.f : 0.f;
  }
#pragma unroll
  for (int off = 1; off < 64; off <<= 1) {
    pos_t += __shfl_xor(pos_t, off);
    neg_t += __shfl_xor(neg_t, off);
    cnt_t += __shfl_xor(cnt_t, off);
  }
  if (lane == 0) { red[w][0] = pos_t; red[w][1] = neg_t; red[w][2] = cnt_t; }
  __syncthreads();
  if (t == 0) {
    partials[(blockIdx.x << 2) + 0] = red[0][0] + red[1][0] + red[2][0] + red[3][0];
    partials[(blockIdx.x << 2) + 1] = red[0][1] + red[1][1] + red[2][1] + red[3][1];
    partials[(blockIdx.x << 2) + 2] = red[0][2] + red[1][2] + red[2][2] + red[3][2];
  }
}

// ---------------- finalize ----------------
__global__ void finalize(const float* __restrict__ parts, int nblk,
                         float* __restrict__ out, int nspans) {
  __shared__ float sp[4], sn[4], sc[4];
  float P = 0.f, Ng = 0.f, C = 0.f;
  for (int i = threadIdx.x; i < nblk; i += 256) {
    P += parts[(i << 2) + 0];
    Ng += parts[(i << 2) + 1];
    C += parts[(i << 2) + 2];
  }
#pragma unroll
  for (int off = 1; off < 64; off <<= 1) {
    P += __shfl_xor(P, off);
    Ng += __shfl_xor(Ng, off);
    C += __shfl_xor(C, off);
  }
  int w = threadIdx.x >> 6;
  if ((threadIdx.x & 63) == 0) { sp[w] = P; sn[w] = Ng; sc[w] = C; }
  __syncthreads();
  if (threadIdx.x == 0) {
    P = sp[0] + sp[1] + sp[2] + sp[3];
    Ng = sn[0] + sn[1] + sn[2] + sn[3];
    C = sc[0] + sc[1] + sc[2] + sc[3];
    float scale = 2.f * C / (float)nspans;
    out[0] = (P + scale * Ng) / (float)nspans;
  }
}

extern "C" void kernel_launch(void* const* d_in, const int* in_sizes, int n_in,
                              void* d_out, int out_size, void* d_ws, size_t ws_size,
                              hipStream_t stream) {
  const float* hidden = (const float*)d_in[0];
  const int* bids     = (const int*)d_in[1];
  const int* begins   = (const int*)d_in[2];
  const int* ends     = (const int*)d_in[3];
  const int* flags    = (const int*)d_in[4];
  const float* weights = (const float*)d_in[5];
  const float* W1 = (const float*)d_in[6];
  const float* b1 = (const float*)d_in[7];
  const float* W2 = (const float*)d_in[8];
  const float* b2 = (const float*)d_in[9];
  float* out = (float*)d_out;
  const int nspans = in_sizes[1];       // 131072
  const int nblk = nspans / SPB;        // 2048

  float* partials = (float*)d_ws;                                    // 32 KiB
  unsigned short* W1b = (unsigned short*)((char*)d_ws + (1 << 18));  // 1 MiB blocked
  unsigned char* Wq = (unsigned char*)((char*)d_ws + (2 << 20));     // 16.8 MiB
  int* ghist = (int*)((char*)d_ws + (19 << 20));                     // 32 ints
  int* gslot = ghist + 32;                                           // 32 ints
  int* sidx  = (int*)((char*)d_ws + (20 << 20));                     // 512 KiB

  hipMemsetAsync(ghist, 0, 64 * sizeof(int), stream);
  prep<<<384, 256, 0, stream>>>(W1, W1b, bids, ghist, nspans);
  span_scatter<<<(nspans + 511) / 512, 256, 0, stream>>>(bids, ghist, gslot,
                                                         sidx, nspans);
  proj_gemm<<<dim3(256, 2), 512, 0, stream>>>(hidden, W1b, Wq);
  span_eval<<<nblk, 256, 0, stream>>>(Wq, sidx, bids, begins, ends, flags,
                                      weights, b1, W2, b2, partials);
  finalize<<<1, 256, 0, stream>>>(partials, nblk, out, nspans);
}

// Round 6
// 166.167 us; speedup vs baseline: 1.1056x; 1.1056x over previous
//
#include <hip/hip_runtime.h>
#include <hip/hip_bf16.h>

// PhraseClassifier R16.
//   R15 post-mortem: (1) manual B pipeline SPILLED (WRITE +18MB scratch) ->
//   reverted. (2) removing XCD swizzle cost ~10us -> restored.
//   New theory: MfmaUtil 14.3% with 5K MFMA-cyc/SIMD => kernel ~35K cyc.
//   LDS-pipe occupancy/CU: K-loop reads 12K + conflicts 9K + epilogue
//   (64 ds_write_b16 + 8 ds_read_b128 per lane!) 14K = ~35K cyc. proj_gemm
//   is LDS-PIPE-BOUND -> explains occupancy/stage/pipeline null results.
//   R16 cuts LDS cycles:
//     - fragment-blocked A LDS [it][mt][64][8] (64KB): A-frag ds_read_b128 =
//       contiguous 1KB/wave, conflict-free by construction (no row-major
//       pitch can be, per R12 algebra). Stage global reads become 16x64B
//       segments (R14 proved stage pattern not binding).
//     - LDS-FREE epilogue: lane packs 4 fp8 per row -> direct dword store.
//       Wq cols land permuted sigma(pos) = w*64+(pos&3)*16+((pos&63)>>2);
//       span_eval gathers b1/w2 through sigma (dot order-invariant).
//   Controls: conflicts 2.36M -> <600K, FETCH/WRITE unchanged.

typedef float f32x4 __attribute__((ext_vector_type(4)));
typedef float f32x2 __attribute__((ext_vector_type(2)));
typedef __bf16 bf16x8 __attribute__((ext_vector_type(8)));
typedef __bf16 bf16x4 __attribute__((ext_vector_type(4)));

__device__ __forceinline__ unsigned short f2bf(float f) {
  unsigned int u = __float_as_uint(f);
  u += 0x7fffu + ((u >> 16) & 1u);   // RNE
  return (unsigned short)(u >> 16);
}
__device__ __forceinline__ float bf2f(unsigned int lo16) {
  return __uint_as_float(lo16 << 16);
}

// ---- prep: W1 blocking (blocks 0..255) + span bid histogram (256..383) ----
__global__ void prep(const float* __restrict__ W1,
                     unsigned short* __restrict__ W1b,
                     const int* __restrict__ bids, int* __restrict__ ghist,
                     int nspans) {
  __shared__ int h[32];
  int t = threadIdx.x;
  if (blockIdx.x < 256) {
    int idx = blockIdx.x * 256 + t;             // 0..65535
    int kc = idx & 3;
    int n  = (idx >> 2) & 511;
    int c  = idx >> 11;
    int k0 = c * 32 + kc * 8;
    unsigned short tmp[8];
#pragma unroll
    for (int j = 0; j < 8; ++j)
      tmp[j] = f2bf(W1[(k0 + j) * 512 + n]);
    *(uint4*)(W1b + c * 16384 + n * 32 + kc * 8) = *(uint4*)tmp;
  } else {
    if (t < 32) h[t] = 0;
    __syncthreads();
    int base = (blockIdx.x - 256) * 1024;
#pragma unroll
    for (int i = 0; i < 4; ++i) {
      int idx = base + t + i * 256;
      if (idx < nspans) atomicAdd(&h[bids[idx]], 1);
    }
    __syncthreads();
    if (t < 32) atomicAdd(&ghist[t], h[t]);
  }
}

// ---- span scatter (counting sort by bid into sidx) ----
__global__ void span_scatter(const int* __restrict__ bids,
                             const int* __restrict__ ghist,
                             int* __restrict__ gslot,
                             int* __restrict__ sidx, int nspans) {
  __shared__ int lh[32], lbase[32], lcur[32];
  int t = threadIdx.x;
  if (t < 32) lh[t] = 0;
  __syncthreads();
  int base = blockIdx.x * 512;
  int myb[2];
#pragma unroll
  for (int i = 0; i < 2; ++i) {
    int idx = base + t + i * 256;
    myb[i] = (idx < nspans) ? bids[idx] : -1;
    if (myb[i] >= 0) atomicAdd(&lh[myb[i]], 1);
  }
  __syncthreads();
  if (t < 32) {
    int pre = 0;
    for (int j = 0; j < t; ++j) pre += ghist[j];   // exclusive prefix
    lbase[t] = pre + atomicAdd(&gslot[t], lh[t]);  // reserve chunk
    lcur[t] = 0;
  }
  __syncthreads();
#pragma unroll
  for (int i = 0; i < 2; ++i) {
    int b = myb[i];
    if (b >= 0) {
      int pos = lbase[b] + atomicAdd(&lcur[b], 1);
      sidx[pos] = base + t + i * 256;
    }
  }
}

// ---------------- proj_gemm v4: 64M x 512N per block, one K-half ------------
// 512 threads / 8 waves, wave w owns cols [w*64, w*64+64): acc 4m x 4n.
// A in fragment-blocked LDS [16 it][4 mt][64 slot][8 kk] (64KB): frag reads
// are contiguous 1KB per wave -> conflict-free. Wave w stages its 0..1 of
// its own (it = 2w, 2w+1) across all 64 rows. Epilogue is LDS-free: direct
// packed-fp8 dword stores in permuted column order sigma.
__global__ __launch_bounds__(512, 4) void proj_gemm(
    const float* __restrict__ hidden,        // [16384][1024]
    const unsigned short* __restrict__ w1b,  // blocked [32][512][32] bf16
    unsigned char* __restrict__ Wq) {        // [16384][1024] fp8, cols perm'd
  __shared__ __align__(16) unsigned short LB[32768];  // 64 KiB

  const int t = threadIdx.x;                 // 0..511
  const int lane = t & 63;
  const int w = t >> 6;                      // 0..7
  const int r0 = blockIdx.x << 6;
  const int hk = blockIdx.y << 9;            // 0 (U) or 512 (V)
  const int q = lane >> 4;                   // k-sub 0..3
  const int m = lane & 15;

  // ---- stage A: wave w covers its two K-tiles (it=2w, 2w+1), all 64 rows.
  // Per instr: lane (kq=lane>>4, sm=lane&15) reads 16B of row sm of the
  // current 16-row group -> 16 x 64B segments (stage pattern non-binding
  // per R14). Write lands fragment-blocked, <=4-way.
  {
    const int kq = lane >> 4;                // 0..3
    const int sm = lane & 15;                // row-within-group
#pragma unroll
    for (int ii = 0; ii < 2; ++ii) {
      const int it = (w << 1) + ii;
#pragma unroll
      for (int mt = 0; mt < 4; ++mt) {
#pragma unroll
        for (int hh = 0; hh < 2; ++hh) {
          const int kk_ = (hh << 4) + (kq << 2);    // k within tile, 0..28
          const float* gp = hidden + ((r0 + (mt << 4) + sm) << 10)
                                   + hk + (it << 5) + kk_;
          float4 f = *(const float4*)gp;
          bf16x4 hv;
          hv[0] = (__bf16)f.x; hv[1] = (__bf16)f.y;
          hv[2] = (__bf16)f.z; hv[3] = (__bf16)f.w;
          const int qq = kk_ >> 3;                  // k-quad
          const int kkr = kk_ & 7;                  // 0 or 4
          *(bf16x4*)(LB + (((it << 2) + mt) << 9)
                        + (((qq << 4) + sm) << 3) + kkr) = hv;
        }
      }
    }
  }
  __syncthreads();

  int boffn[4];
#pragma unroll
  for (int nt = 0; nt < 4; ++nt)
    boffn[nt] = (((w << 6) + (nt << 4) + m) << 5) + (q << 3);
  const unsigned short* w1base = w1b + (blockIdx.y << 18);

  f32x4 acc[4][4];
#pragma unroll
  for (int i = 0; i < 4; ++i)
#pragma unroll
    for (int j = 0; j < 4; ++j) acc[i][j] = (f32x4){0.f, 0.f, 0.f, 0.f};

#pragma unroll
  for (int it = 0; it < 16; ++it) {
    const unsigned short* bt = w1base + (it << 14);   // tile it
    bf16x8 bfr[4];
#pragma unroll
    for (int nt = 0; nt < 4; ++nt)
      bfr[nt] = *(const bf16x8*)(bt + boffn[nt]);
    bf16x8 af[4];
#pragma unroll
    for (int mt = 0; mt < 4; ++mt)
      af[mt] = *(const bf16x8*)(LB + (((it << 2) + mt) << 9)
                                   + (((q << 4) + m) << 3));
#pragma unroll
    for (int mt = 0; mt < 4; ++mt)
#pragma unroll
      for (int nt = 0; nt < 4; ++nt)
        acc[mt][nt] = __builtin_amdgcn_mfma_f32_16x16x32_bf16(af[mt], bfr[nt],
                                                              acc[mt][nt], 0, 0, 0);
  }

  // ---- epilogue: LDS-free. Lane (q,m) owns rows mt*16+q*4+r, packs its 4
  // nt-values into one fp8 dword at byte cb = w*64 + m*4. Column at byte
  // pos p (within 512-half) is sigma(p) = (p>>6)*64 + (p&3)*16 + ((p&63)>>2).
  {
    const int cb = (w << 6) + (m << 2);
#pragma unroll
    for (int mt = 0; mt < 4; ++mt) {
#pragma unroll
      for (int r = 0; r < 4; ++r) {
        unsigned int o = __builtin_amdgcn_cvt_pk_fp8_f32(
            acc[mt][0][r], acc[mt][1][r], 0, false);
        o = __builtin_amdgcn_cvt_pk_fp8_f32(
            acc[mt][2][r], acc[mt][3][r], o, true);
        int grow = r0 + (mt << 4) + (q << 2) + r;
        if (hk == 0) {
          *(unsigned int*)(Wq + (grow << 10) + cb) = o;              // U[r]
        } else if (grow >= 32) {
          *(unsigned int*)(Wq + ((grow - 32) << 10) + 512 + cb) = o; // V
        }
      }
    }
  }
}

// ---------------- span_eval: 1 span per half-wave, bid-sorted + XCD swizzle ----
#define SPB 64
__global__ __launch_bounds__(256) void span_eval(
    const unsigned char* __restrict__ Wq,
    const int* __restrict__ sidx,
    const int* __restrict__ bids, const int* __restrict__ begins,
    const int* __restrict__ ends, const int* __restrict__ flags,
    const float* __restrict__ weights,
    const float* __restrict__ b1, const float* __restrict__ w2,
    const float* __restrict__ b2, float* __restrict__ partials) {
  __shared__ int oB[SPB], oE[SPB], sfl[SPB];
  __shared__ float swt[SPB];
  __shared__ float red[4][3];
  const int t = threadIdx.x;
  const int lane = t & 63;
  const int w = t >> 6;
  const int h = lane >> 5;          // half-wave
  const int hl = lane & 31;

  // XCD swizzle (restored): each XCD gets a contiguous chunk of the
  // bid-sorted span order -> ~4 bids = 2MB slab per L2.
  const int nblk = gridDim.x;
  int lb = blockIdx.x;
  if ((nblk & 7) == 0) {
    const int cpx = nblk >> 3;
    lb = (blockIdx.x & 7) * cpx + (blockIdx.x >> 3);
  }
  const int sbase = lb * SPB;

  if (t < SPB) {
    int s = sidx[sbase + t];
    int b = bids[s], bg = begins[s], en = ends[s];
    oB[t] = (((bg - 1) << 5) + b) << 10;   // row b-1: [U[b-1] | V[b]]
    oE[t] = (((en - 1) << 5) + b) << 10;   // row e-1: [U[e-1] | V[e]]
    sfl[t] = flags[s];
    swt[t] = weights[s];
  }
  __syncthreads();

  const int sp0 = ((w << 1) + h) << 3;   // my half-wave's first span (block-local)
  const int c0 = hl << 4;                // 16 bytes per lane
  // b1/w2 gathered through the storage permutation sigma:
  // byte pos p = c0+j -> col (hl>>2)*64 + (j&3)*16 + (hl&3)*4 + (j>>2)
  float b1v[16], w2v[16];
#pragma unroll
  for (int j = 0; j < 16; ++j) {
    int colp = ((hl >> 2) << 6) + ((j & 3) << 4) + ((hl & 3) << 2) + (j >> 2);
    b1v[j] = b1[colp];
    w2v[j] = w2[colp];
  }

  auto dec = [](unsigned int v, float* f) {
    f32x2 a = __builtin_amdgcn_cvt_pk_f32_fp8(v, false);
    f32x2 b = __builtin_amdgcn_cvt_pk_f32_fp8(v, true);
    f[0] = a[0]; f[1] = a[1]; f[2] = b[0]; f[3] = b[1];
  };

  uint4 BU[3], BV[3], EU[3], EV[3];
  auto ld = [&](int slot, int j) {
    int ob = oB[sp0 + j], oe = oE[sp0 + j];
    BU[slot] = *(const uint4*)(Wq + ob + c0);        // U[b-1] chunk
    BV[slot] = *(const uint4*)(Wq + ob + 512 + c0);  // V[b]   chunk
    EU[slot] = *(const uint4*)(Wq + oe + c0);        // U[e-1] chunk
    EV[slot] = *(const uint4*)(Wq + oe + 512 + c0);  // V[e]   chunk
  };
  ld(0, 0); ld(1, 1); ld(2, 2);

  float mylogit = 0.f;
#pragma unroll
  for (int j = 0; j < 8; ++j) {
    const int slot = j % 3;
    float buf[16], bvf[16], euf[16], evf[16];
    dec(BU[slot].x, buf); dec(BU[slot].y, buf + 4);
    dec(BU[slot].z, buf + 8); dec(BU[slot].w, buf + 12);
    dec(BV[slot].x, bvf); dec(BV[slot].y, bvf + 4);
    dec(BV[slot].z, bvf + 8); dec(BV[slot].w, bvf + 12);
    dec(EU[slot].x, euf); dec(EU[slot].y, euf + 4);
    dec(EU[slot].z, euf + 8); dec(EU[slot].w, euf + 12);
    dec(EV[slot].x, evf); dec(EV[slot].y, evf + 4);
    dec(EV[slot].z, evf + 8); dec(EV[slot].w, evf + 12);
    if (j + 3 < 8) ld(slot, j + 3);
    float sv = 0.f;
#pragma unroll
    for (int k = 0; k < 16; ++k) {
      float zp = euf[k] - buf[k] + bvf[k] - evf[k] + b1v[k];
      sv += fmaxf(zp, 0.f) * w2v[k];
    }
    sv += __shfl_xor(sv, 1);
    sv += __shfl_xor(sv, 2);
    sv += __shfl_xor(sv, 4);
    sv += __shfl_xor(sv, 8);
    sv += __shfl_xor(sv, 16);       // reduce within half-wave
    if (hl == j) mylogit = sv;      // lane h*32+j parks span sp0+j
  }

  // span w*16+l (l<16) parked at lane ((l&8)<<2)+(l&7)
  mylogit = __shfl(mylogit, ((lane & 8) << 2) + (lane & 7));

  float pos_t = 0.f, neg_t = 0.f, cnt_t = 0.f;
  if (lane < 16) {
    int sl = (w << 4) + lane;       // block-local span id
    float logit = mylogit + b2[0];
    float p = 1.f / (1.f + expf(-logit));
    p = fminf(fmaxf(p, 1e-7f), 1.f - 1e-7f);
    int fl = sfl[sl];
    float bce = (fl == 1) ? -logf(p) : -logf(1.f - p);
    float term = swt[sl] * bce;
    pos_t = (fl == 1) ? term : 0.f;
    neg_t = (fl == 1) ? 0.f : term;
    cnt_t = (fl == 1) ? 1.f : 0.f;
  }
#pragma unroll
  for (int off = 1; off < 64; off <<= 1) {
    pos_t += __shfl_xor(pos_t, off);
    neg_t += __shfl_xor(neg_t, off);
    cnt_t += __shfl_xor(cnt_t, off);
  }
  if (lane == 0) { red[w][0] = pos_t; red[w][1] = neg_t; red[w][2] = cnt_t; }
  __syncthreads();
  if (t == 0) {
    partials[(blockIdx.x << 2) + 0] = red[0][0] + red[1][0] + red[2][0] + red[3][0];
    partials[(blockIdx.x << 2) + 1] = red[0][1] + red[1][1] + red[2][1] + red[3][1];
    partials[(blockIdx.x << 2) + 2] = red[0][2] + red[1][2] + red[2][2] + red[3][2];
  }
}

// ---------------- finalize ----------------
__global__ void finalize(const float* __restrict__ parts, int nblk,
                         float* __restrict__ out, int nspans) {
  __shared__ float sp[4], sn[4], sc[4];
  float P = 0.f, Ng = 0.f, C = 0.f;
  for (int i = threadIdx.x; i < nblk; i += 256) {
    P += parts[(i << 2) + 0];
    Ng += parts[(i << 2) + 1];
    C += parts[(i << 2) + 2];
  }
#pragma unroll
  for (int off = 1; off < 64; off <<= 1) {
    P += __shfl_xor(P, off);
    Ng += __shfl_xor(Ng, off);
    C += __shfl_xor(C, off);
  }
  int w = threadIdx.x >> 6;
  if ((threadIdx.x & 63) == 0) { sp[w] = P; sn[w] = Ng; sc[w] = C; }
  __syncthreads();
  if (threadIdx.x == 0) {
    P = sp[0] + sp[1] + sp[2] + sp[3];
    Ng = sn[0] + sn[1] + sn[2] + sn[3];
    C = sc[0] + sc[1] + sc[2] + sc[3];
    float scale = 2.f * C / (float)nspans;
    out[0] = (P + scale * Ng) / (float)nspans;
  }
}

extern "C" void kernel_launch(void* const* d_in, const int* in_sizes, int n_in,
                              void* d_out, int out_size, void* d_ws, size_t ws_size,
                              hipStream_t stream) {
  const float* hidden = (const float*)d_in[0];
  const int* bids     = (const int*)d_in[1];
  const int* begins   = (const int*)d_in[2];
  const int* ends     = (const int*)d_in[3];
  const int* flags    = (const int*)d_in[4];
  const float* weights = (const float*)d_in[5];
  const float* W1 = (const float*)d_in[6];
  const float* b1 = (const float*)d_in[7];
  const float* W2 = (const float*)d_in[8];
  const float* b2 = (const float*)d_in[9];
  float* out = (float*)d_out;
  const int nspans = in_sizes[1];       // 131072
  const int nblk = nspans / SPB;        // 2048

  float* partials = (float*)d_ws;                                    // 32 KiB
  unsigned short* W1b = (unsigned short*)((char*)d_ws + (1 << 18));  // 1 MiB blocked
  unsigned char* Wq = (unsigned char*)((char*)d_ws + (2 << 20));     // 16.8 MiB
  int* ghist = (int*)((char*)d_ws + (19 << 20));                     // 32 ints
  int* gslot = ghist + 32;                                           // 32 ints
  int* sidx  = (int*)((char*)d_ws + (20 << 20));                     // 512 KiB

  hipMemsetAsync(ghist, 0, 64 * sizeof(int), stream);
  prep<<<384, 256, 0, stream>>>(W1, W1b, bids, ghist, nspans);
  span_scatter<<<(nspans + 511) / 512, 256, 0, stream>>>(bids, ghist, gslot,
                                                         sidx, nspans);
  proj_gemm<<<dim3(256, 2), 512, 0, stream>>>(hidden, W1b, Wq);
  span_eval<<<nblk, 256, 0, stream>>>(Wq, sidx, bids, begins, ends, flags,
                                      weights, b1, W2, b2, partials);
  finalize<<<1, 256, 0, stream>>>(partials, nblk, out, nspans);
}